// Round 2
// baseline (195.494 us; speedup 1.0000x reference)
//
#include <hip/hip_runtime.h>

#define HID 64
#define TT  128
#define NROWS 8192
#define NGRP (NROWS / 16)   // 512 blocks of 16 rows; 2 blocks/CU
#define LOG2E 1.44269504088896f

typedef _Float16 half8 __attribute__((ext_vector_type(8)));
typedef float    f32x4 __attribute__((ext_vector_type(4)));

// ---------- pre-pass: length-sort rows into complementary-paired groups ----------
// ws layout (ints): lens[8192] | perm[8192] | hist[129] | offs[129]

__global__ void k_len(const int* __restrict__ mask, int* __restrict__ lens,
                      int* __restrict__ hist) {
    const int row = blockIdx.x * 4 + (threadIdx.x >> 6);
    const int l   = threadIdx.x & 63;
    const int* mrow = mask + row * TT;
    int c = (mrow[l] != 0) + (mrow[l + 64] != 0);
    #pragma unroll
    for (int k = 32; k >= 1; k >>= 1) c += __shfl_xor(c, k);
    if (l == 0) { lens[row] = c; atomicAdd(&hist[c], 1); }
}

__global__ void k_prefix(const int* __restrict__ hist, int* __restrict__ offs) {
    if (threadIdx.x == 0) {
        int s = 0;
        for (int i = 0; i <= TT; i++) { offs[i] = s; s += hist[i]; }
    }
}

// descending length rank d -> group gd = d/16; pair complementary groups so
// blocks b and b+256 (same CU under round-robin dispatch) get ranks k, 511-k.
__global__ void k_scatter(const int* __restrict__ lens, int* __restrict__ offs,
                          int* __restrict__ perm) {
    const int row = blockIdx.x * 256 + threadIdx.x;
    const int L   = lens[row];
    const int pos = atomicAdd(&offs[L], 1);       // ascending rank
    const int d   = NROWS - 1 - pos;              // descending rank
    const int gd  = d >> 4, r = d & 15;
    const int b   = (gd < 256) ? gd : 767 - gd;
    perm[b * 16 + r] = row;
}

// ---------- main GRU kernel (R11 step loop + permuted rows) ----------
__global__ __launch_bounds__(256, 2) void gru_fused(
    const int* __restrict__ actor_ids, const int* __restrict__ action_ids,
    const int* __restrict__ street_ids, const float* __restrict__ bet,
    const float* __restrict__ E_actor, const float* __restrict__ E_action,
    const float* __restrict__ E_street, const float* __restrict__ W_proj,
    const float* __restrict__ b_proj, const float* __restrict__ W_ih,
    const float* __restrict__ b_ih, const float* __restrict__ W_hh,
    const float* __restrict__ b_hh, const int* __restrict__ perm,
    const int* __restrict__ lens, float* __restrict__ out)
{
    __shared__ __align__(16) union {
        float wfs[192][32];                           // startup: fused W_f (scaled)
        struct {
            int pb[TT][17];                           // ids|bet16, padded
            __align__(16) _Float16 hb[2][16][72];     // h f16 dbuf, stride 72
            int Lsh[16];
            int Psh[16];
        } c;
    } A;
    __shared__ __align__(16) _Float16 embl[144];
    __shared__ float bfs[192];                        // raw fused bias b_f

    const int tid = threadIdx.x;
    const int wv  = tid >> 6;        // wave = hid quarter
    const int l   = tid & 63;
    const int q   = l >> 4;          // quad
    const int n   = l & 15;          // batch col within group
    const int g   = blockIdx.x;

    // embedding rows: 0..6 actor, 7..10 action, 11..15 street(+pad), 16 zero
    for (int i = tid; i < 136; i += 256) {
        int r = i >> 3, m = i & 7;
        float v = 0.f;
        if (r < 7)       v = E_actor[r * 8 + m];
        else if (r < 11) v = E_action[(r - 7) * 8 + m];
        else if (r < 16) v = (m < 4) ? E_street[(r - 11) * 4 + m] : 0.f;
        embl[i] = (_Float16)v;
    }

    // ---- startup: fused input weights into LDS ----
    if (tid < 192) {
        const int j = tid;
        float wf[21];
        #pragma unroll
        for (int m = 0; m < 21; m++) wf[m] = 0.f;
        float bf = b_ih[j];
        for (int k = 0; k < 32; k++) {
            const float w = W_ih[j * 32 + k];
            bf += w * b_proj[k];
            #pragma unroll
            for (int m = 0; m < 21; m++) wf[m] += w * W_proj[k * 21 + m];
        }
        const float s = (j < 128) ? LOG2E : 2.f * LOG2E;
        #pragma unroll
        for (int m = 0; m < 21; m++) A.wfs[j][m] = wf[m] * s;
        #pragma unroll
        for (int m = 21; m < 32; m++) A.wfs[j][m] = 0.f;
        bfs[j] = bf;
    }
    __syncthreads();

    // ---- extract per-lane A-fragments + biases (registers) ----
    half8 Af[3], Ah[3][2];
    {
        const int m16 = l & 15, kq = l >> 4;
        #pragma unroll
        for (int g3 = 0; g3 < 3; g3++) {
            const int jr = g3 * 64 + wv * 16 + m16;
            _Float16 v[8];
            #pragma unroll
            for (int m = 0; m < 8; m++) v[m] = (_Float16)A.wfs[jr][kq * 8 + m];
            Af[g3] = *(half8*)v;
            const float s = (g3 < 2) ? LOG2E : 2.f * LOG2E;
            #pragma unroll
            for (int kt = 0; kt < 2; kt++) {
                _Float16 w[8];
                #pragma unroll
                for (int m = 0; m < 8; m++)
                    w[m] = (_Float16)(W_hh[jr * HID + kt * 32 + kq * 8 + m] * s);
                Ah[g3][kt] = *(half8*)w;
            }
        }
    }
    f32x4 biasR, biasZ, biasX, biasH;
    #pragma unroll
    for (int e = 0; e < 4; e++) {
        const int idx = 16 * wv + 4 * q + e;
        biasR[e] = (bfs[idx]      + b_hh[idx])      * LOG2E;
        biasZ[e] = (bfs[64 + idx] + b_hh[64 + idx]) * LOG2E;
        biasX[e] = bfs[128 + idx]  * (2.f * LOG2E);
        biasH[e] = b_hh[128 + idx] * (2.f * LOG2E);
    }
    __syncthreads();   // wfs dead; arena becomes pb/hb

    // ---- stage pb via perm, zero hb, fetch lengths ----
    for (int i = tid; i < 2 * 16 * 72 / 2; i += 256) ((int*)A.c.hb)[i] = 0;
    {
        const int r = tid >> 4, tl = tid & 15;
        const int prow = perm[g * 16 + r];
        const int base = prow * TT;
        #pragma unroll
        for (int i = 0; i < 8; i++) {
            const int t = tl + 16 * i;
            const int a = actor_ids[base + t], c = action_ids[base + t];
            const int s = street_ids[base + t];
            const _Float16 f16 = (_Float16)bet[base + t];
            const unsigned fb = (unsigned)*(const unsigned short*)&f16;
            A.c.pb[t][r] = (int)(a | (c << 3) | (s << 5) | (fb << 16));
        }
        if (tl == 0) { A.c.Lsh[r] = lens[prow]; A.c.Psh[r] = prow; }
    }
    __syncthreads();

    const int Ln = A.c.Lsh[n];
    int Lmax = Ln;     // butterfly max over the 16 n-columns (wave-uniform)
    #pragma unroll
    for (int k = 1; k < 16; k <<= 1) {
        const int o = __shfl_xor(Lmax, k);
        Lmax = (o > Lmax) ? o : Lmax;
    }

    const bool isq2 = (q == 2);
    const int sh = (q == 1) ? 3 : (q == 2) ? 5 : 0;
    const int mk = (q == 1) ? 3 : (q == 3) ? 0 : 7;
    const int of = (q == 1) ? 7 : (q == 2) ? 11 : (q == 3) ? 16 : 0;

    float h[4] = {0.f, 0.f, 0.f, 0.f};

    // prime step-0 x-side accumulators
    f32x4 xR, xZ, xX;
    {
        const int p = A.c.pb[0][n];
        const int eidx = ((p >> sh) & mk) + of;
        half8 Bf = *(const half8*)&embl[eidx * 8];
        uint4* bu = (uint4*)&Bf;
        bu->z = isq2 ? ((unsigned)p >> 16) : bu->z;   // {bet16, 0} at k=20,21
        xR = __builtin_amdgcn_mfma_f32_16x16x32_f16(Af[0], Bf, biasR, 0, 0, 0);
        xZ = __builtin_amdgcn_mfma_f32_16x16x32_f16(Af[1], Bf, biasZ, 0, 0, 0);
        xX = __builtin_amdgcn_mfma_f32_16x16x32_f16(Af[2], Bf, biasX, 0, 0, 0);
    }

    for (int t = 0; t < Lmax; t++) {
        const int buf = t & 1;
        const half8 Bh0 = *(const half8*)&A.c.hb[buf][n][q * 8];
        const half8 Bh1 = *(const half8*)&A.c.hb[buf][n][32 + q * 8];
        // K-tiles chained through the C operand (3 independent depth-2 chains)
        f32x4 aR = __builtin_amdgcn_mfma_f32_16x16x32_f16(Ah[0][0], Bh0, xR, 0, 0, 0);
        aR = __builtin_amdgcn_mfma_f32_16x16x32_f16(Ah[0][1], Bh1, aR, 0, 0, 0);
        f32x4 aZ = __builtin_amdgcn_mfma_f32_16x16x32_f16(Ah[1][0], Bh0, xZ, 0, 0, 0);
        aZ = __builtin_amdgcn_mfma_f32_16x16x32_f16(Ah[1][1], Bh1, aZ, 0, 0, 0);
        f32x4 aH = __builtin_amdgcn_mfma_f32_16x16x32_f16(Ah[2][0], Bh0, biasH, 0, 0, 0);
        aH = __builtin_amdgcn_mfma_f32_16x16x32_f16(Ah[2][1], Bh1, aH, 0, 0, 0);
        const f32x4 aXc = xX;

        // prefetch step t+1 x-side (independent of this step's h)
        {
            const int tn = (t + 1 < TT) ? t + 1 : TT - 1;
            const int p = A.c.pb[tn][n];
            const int eidx = ((p >> sh) & mk) + of;
            half8 Bf = *(const half8*)&embl[eidx * 8];
            uint4* bu = (uint4*)&Bf;
            bu->z = isq2 ? ((unsigned)p >> 16) : bu->z;
            xR = __builtin_amdgcn_mfma_f32_16x16x32_f16(Af[0], Bf, biasR, 0, 0, 0);
            xZ = __builtin_amdgcn_mfma_f32_16x16x32_f16(Af[1], Bf, biasZ, 0, 0, 0);
            xX = __builtin_amdgcn_mfma_f32_16x16x32_f16(Af[2], Bf, biasX, 0, 0, 0);
        }

        const bool live = (t < Ln);
        _Float16 hp[4];
        #pragma unroll
        for (int e = 0; e < 4; e++) {
            const float r = __builtin_amdgcn_rcpf(1.f + __builtin_amdgcn_exp2f(-aR[e]));
            const float z = __builtin_amdgcn_rcpf(1.f + __builtin_amdgcn_exp2f(-aZ[e]));
            const float y2 = aXc[e] + r * aH[e];           // = 2*log2e*y
            const float nn = 1.f - 2.f * __builtin_amdgcn_rcpf(1.f + __builtin_amdgcn_exp2f(y2));
            const float hv = nn + z * (h[e] - nn);
            h[e] = live ? hv : h[e];
            hp[e] = (_Float16)h[e];
        }
        *(uint2*)&A.c.hb[buf ^ 1][n][16 * wv + 4 * q] = *(uint2*)hp;
        __syncthreads();
    }

    const int prow = A.c.Psh[n];
    float4 o = make_float4(h[0], h[1], h[2], h[3]);
    *(float4*)&out[prow * HID + 16 * wv + 4 * q] = o;
}

extern "C" void kernel_launch(void* const* d_in, const int* in_sizes, int n_in,
                              void* d_out, int out_size, void* d_ws, size_t ws_size,
                              hipStream_t stream) {
    const int*   actor_ids  = (const int*)d_in[0];
    const int*   action_ids = (const int*)d_in[1];
    const int*   street_ids = (const int*)d_in[2];
    const float* bet        = (const float*)d_in[3];
    const int*   vmask      = (const int*)d_in[4];
    const float* E_actor    = (const float*)d_in[5];
    const float* E_action   = (const float*)d_in[6];
    const float* E_street   = (const float*)d_in[7];
    const float* W_proj     = (const float*)d_in[8];
    const float* b_proj     = (const float*)d_in[9];
    const float* W_ih       = (const float*)d_in[10];
    const float* W_hh       = (const float*)d_in[11];
    const float* b_ih       = (const float*)d_in[12];
    const float* b_hh       = (const float*)d_in[13];
    float*       out        = (float*)d_out;

    int* ws   = (int*)d_ws;
    int* lens = ws;
    int* perm = ws + NROWS;
    int* hist = ws + 2 * NROWS;
    int* offs = ws + 2 * NROWS + 160;

    hipMemsetAsync(hist, 0, (TT + 1) * sizeof(int), stream);
    k_len<<<NROWS / 4, 256, 0, stream>>>(vmask, lens, hist);
    k_prefix<<<1, 64, 0, stream>>>(hist, offs);
    k_scatter<<<NROWS / 256, 256, 0, stream>>>(lens, offs, perm);

    gru_fused<<<NGRP, 256, 0, stream>>>(actor_ids, action_ids, street_ids, bet,
                                        E_actor, E_action, E_street,
                                        W_proj, b_proj, W_ih, b_ih, W_hh, b_hh,
                                        perm, lens, out);
}

// Round 3
// 166.549 us; speedup vs baseline: 1.1738x; 1.1738x over previous
//
#include <hip/hip_runtime.h>

#define HID 64
#define TT  128
#define NROWS 8192
#define NGRP (NROWS / 16)   // 512 blocks of 16 rows; 2 blocks/CU
#define LOG2E 1.44269504088896f

typedef _Float16 half8 __attribute__((ext_vector_type(8)));
typedef float    f32x4 __attribute__((ext_vector_type(4)));

// ---------- pre-pass: length-sort rows into complementary-paired groups ----------
// ws layout (ints): lens[8192] | perm[8192]

__global__ void k_len(const int* __restrict__ mask, int* __restrict__ lens) {
    const int row = blockIdx.x * 4 + (threadIdx.x >> 6);
    const int l   = threadIdx.x & 63;
    const int* mrow = mask + row * TT;
    int c = (mrow[l] != 0) + (mrow[l + 64] != 0);
    #pragma unroll
    for (int k = 32; k >= 1; k >>= 1) c += __shfl_xor(c, k);
    if (l == 0) lens[row] = c;
}

// Single block: LDS histogram -> LDS prefix -> LDS-atomic scatter.
// Descending length rank d -> group gd = d/16; pair complementary groups so
// blocks b and b+256 (same CU under round-robin dispatch) get ranks k, 511-k.
__global__ __launch_bounds__(1024) void k_sort(const int* __restrict__ lens,
                                               int* __restrict__ perm) {
    __shared__ int hist[TT + 1];
    __shared__ int offs[TT + 1];
    const int tid = threadIdx.x;
    if (tid <= TT) hist[tid] = 0;
    __syncthreads();
    int myL[8];
    #pragma unroll
    for (int i = 0; i < 8; i++) {
        myL[i] = lens[tid + 1024 * i];
        atomicAdd(&hist[myL[i]], 1);
    }
    __syncthreads();
    if (tid <= TT) {
        int s = 0;
        for (int j = 0; j < tid; j++) s += hist[j];
        offs[tid] = s;
    }
    __syncthreads();
    #pragma unroll
    for (int i = 0; i < 8; i++) {
        const int pos = atomicAdd(&offs[myL[i]], 1);      // ascending rank
        const int d   = NROWS - 1 - pos;                  // descending rank
        const int gd  = d >> 4, r = d & 15;
        const int b   = (gd < 256) ? gd : 767 - gd;
        perm[b * 16 + r] = tid + 1024 * i;
    }
}

// ---------- main GRU kernel (R11 step loop + permuted rows) ----------
__global__ __launch_bounds__(256, 2) void gru_fused(
    const int* __restrict__ actor_ids, const int* __restrict__ action_ids,
    const int* __restrict__ street_ids, const float* __restrict__ bet,
    const float* __restrict__ E_actor, const float* __restrict__ E_action,
    const float* __restrict__ E_street, const float* __restrict__ W_proj,
    const float* __restrict__ b_proj, const float* __restrict__ W_ih,
    const float* __restrict__ b_ih, const float* __restrict__ W_hh,
    const float* __restrict__ b_hh, const int* __restrict__ perm,
    const int* __restrict__ lens, float* __restrict__ out)
{
    __shared__ __align__(16) union {
        float wfs[192][32];                           // startup: fused W_f (scaled)
        struct {
            int pb[TT][17];                           // ids|bet16, padded
            __align__(16) _Float16 hb[2][16][72];     // h f16 dbuf, stride 72
            int Lsh[16];
            int Psh[16];
        } c;
    } A;
    __shared__ __align__(16) _Float16 embl[144];
    __shared__ float bfs[192];                        // raw fused bias b_f

    const int tid = threadIdx.x;
    const int wv  = tid >> 6;        // wave = hid quarter
    const int l   = tid & 63;
    const int q   = l >> 4;          // quad
    const int n   = l & 15;          // batch col within group
    const int g   = blockIdx.x;

    // embedding rows: 0..6 actor, 7..10 action, 11..15 street(+pad), 16 zero
    for (int i = tid; i < 136; i += 256) {
        int r = i >> 3, m = i & 7;
        float v = 0.f;
        if (r < 7)       v = E_actor[r * 8 + m];
        else if (r < 11) v = E_action[(r - 7) * 8 + m];
        else if (r < 16) v = (m < 4) ? E_street[(r - 11) * 4 + m] : 0.f;
        embl[i] = (_Float16)v;
    }

    // ---- startup: fused input weights into LDS ----
    if (tid < 192) {
        const int j = tid;
        float wf[21];
        #pragma unroll
        for (int m = 0; m < 21; m++) wf[m] = 0.f;
        float bf = b_ih[j];
        for (int k = 0; k < 32; k++) {
            const float w = W_ih[j * 32 + k];
            bf += w * b_proj[k];
            #pragma unroll
            for (int m = 0; m < 21; m++) wf[m] += w * W_proj[k * 21 + m];
        }
        const float s = (j < 128) ? LOG2E : 2.f * LOG2E;
        #pragma unroll
        for (int m = 0; m < 21; m++) A.wfs[j][m] = wf[m] * s;
        #pragma unroll
        for (int m = 21; m < 32; m++) A.wfs[j][m] = 0.f;
        bfs[j] = bf;
    }
    __syncthreads();

    // ---- extract per-lane A-fragments + biases (registers) ----
    half8 Af[3], Ah[3][2];
    {
        const int m16 = l & 15, kq = l >> 4;
        #pragma unroll
        for (int g3 = 0; g3 < 3; g3++) {
            const int jr = g3 * 64 + wv * 16 + m16;
            _Float16 v[8];
            #pragma unroll
            for (int m = 0; m < 8; m++) v[m] = (_Float16)A.wfs[jr][kq * 8 + m];
            Af[g3] = *(half8*)v;
            const float s = (g3 < 2) ? LOG2E : 2.f * LOG2E;
            #pragma unroll
            for (int kt = 0; kt < 2; kt++) {
                _Float16 w[8];
                #pragma unroll
                for (int m = 0; m < 8; m++)
                    w[m] = (_Float16)(W_hh[jr * HID + kt * 32 + kq * 8 + m] * s);
                Ah[g3][kt] = *(half8*)w;
            }
        }
    }
    f32x4 biasR, biasZ, biasX, biasH;
    #pragma unroll
    for (int e = 0; e < 4; e++) {
        const int idx = 16 * wv + 4 * q + e;
        biasR[e] = (bfs[idx]      + b_hh[idx])      * LOG2E;
        biasZ[e] = (bfs[64 + idx] + b_hh[64 + idx]) * LOG2E;
        biasX[e] = bfs[128 + idx]  * (2.f * LOG2E);
        biasH[e] = b_hh[128 + idx] * (2.f * LOG2E);
    }
    __syncthreads();   // wfs dead; arena becomes pb/hb

    // ---- stage pb via perm, zero hb, fetch lengths ----
    for (int i = tid; i < 2 * 16 * 72 / 2; i += 256) ((int*)A.c.hb)[i] = 0;
    {
        const int r = tid >> 4, tl = tid & 15;
        const int prow = perm[g * 16 + r];
        const int base = prow * TT;
        #pragma unroll
        for (int i = 0; i < 8; i++) {
            const int t = tl + 16 * i;
            const int a = actor_ids[base + t], c = action_ids[base + t];
            const int s = street_ids[base + t];
            const _Float16 f16 = (_Float16)bet[base + t];
            const unsigned fb = (unsigned)*(const unsigned short*)&f16;
            A.c.pb[t][r] = (int)(a | (c << 3) | (s << 5) | (fb << 16));
        }
        if (tl == 0) { A.c.Lsh[r] = lens[prow]; A.c.Psh[r] = prow; }
    }
    __syncthreads();

    const int Ln = A.c.Lsh[n];
    int Lmax = Ln;     // butterfly max over the 16 n-columns (wave-uniform)
    #pragma unroll
    for (int k = 1; k < 16; k <<= 1) {
        const int o = __shfl_xor(Lmax, k);
        Lmax = (o > Lmax) ? o : Lmax;
    }

    const bool isq2 = (q == 2);
    const int sh = (q == 1) ? 3 : (q == 2) ? 5 : 0;
    const int mk = (q == 1) ? 3 : (q == 3) ? 0 : 7;
    const int of = (q == 1) ? 7 : (q == 2) ? 11 : (q == 3) ? 16 : 0;

    float h[4] = {0.f, 0.f, 0.f, 0.f};
    const f32x4 zero4 = {0.f, 0.f, 0.f, 0.f};

    // prime step-0 x-side accumulators
    f32x4 xR, xZ, xX;
    {
        const int p = A.c.pb[0][n];
        const int eidx = ((p >> sh) & mk) + of;
        half8 Bf = *(const half8*)&embl[eidx * 8];
        uint4* bu = (uint4*)&Bf;
        bu->z = isq2 ? ((unsigned)p >> 16) : bu->z;   // {bet16, 0} at k=20,21
        xR = __builtin_amdgcn_mfma_f32_16x16x32_f16(Af[0], Bf, biasR, 0, 0, 0);
        xZ = __builtin_amdgcn_mfma_f32_16x16x32_f16(Af[1], Bf, biasZ, 0, 0, 0);
        xX = __builtin_amdgcn_mfma_f32_16x16x32_f16(Af[2], Bf, biasX, 0, 0, 0);
    }

    for (int t = 0; t < Lmax; t++) {
        const int buf = t & 1;
        const half8 Bh0 = *(const half8*)&A.c.hb[buf][n][q * 8];
        const half8 Bh1 = *(const half8*)&A.c.hb[buf][n][32 + q * 8];
        // R gate: two independent MFMAs + VALU add (shortens the critical
        // chain r -> y2 -> exp2 -> ... by ~1 MFMA latency). Z/H have slack:
        // keep them C-chained (cheaper on issue).
        f32x4 aRa = __builtin_amdgcn_mfma_f32_16x16x32_f16(Ah[0][0], Bh0, xR, 0, 0, 0);
        f32x4 aRb = __builtin_amdgcn_mfma_f32_16x16x32_f16(Ah[0][1], Bh1, zero4, 0, 0, 0);
        f32x4 aZ = __builtin_amdgcn_mfma_f32_16x16x32_f16(Ah[1][0], Bh0, xZ, 0, 0, 0);
        aZ = __builtin_amdgcn_mfma_f32_16x16x32_f16(Ah[1][1], Bh1, aZ, 0, 0, 0);
        f32x4 aH = __builtin_amdgcn_mfma_f32_16x16x32_f16(Ah[2][0], Bh0, biasH, 0, 0, 0);
        aH = __builtin_amdgcn_mfma_f32_16x16x32_f16(Ah[2][1], Bh1, aH, 0, 0, 0);
        const f32x4 aR = aRa + aRb;
        const f32x4 aXc = xX;

        // prefetch step t+1 x-side (independent of this step's h)
        {
            const int tn = (t + 1 < TT) ? t + 1 : TT - 1;
            const int p = A.c.pb[tn][n];
            const int eidx = ((p >> sh) & mk) + of;
            half8 Bf = *(const half8*)&embl[eidx * 8];
            uint4* bu = (uint4*)&Bf;
            bu->z = isq2 ? ((unsigned)p >> 16) : bu->z;
            xR = __builtin_amdgcn_mfma_f32_16x16x32_f16(Af[0], Bf, biasR, 0, 0, 0);
            xZ = __builtin_amdgcn_mfma_f32_16x16x32_f16(Af[1], Bf, biasZ, 0, 0, 0);
            xX = __builtin_amdgcn_mfma_f32_16x16x32_f16(Af[2], Bf, biasX, 0, 0, 0);
        }

        const bool live = (t < Ln);
        _Float16 hp[4];
        #pragma unroll
        for (int e = 0; e < 4; e++) {
            const float r = __builtin_amdgcn_rcpf(1.f + __builtin_amdgcn_exp2f(-aR[e]));
            const float z = __builtin_amdgcn_rcpf(1.f + __builtin_amdgcn_exp2f(-aZ[e]));
            const float y2 = aXc[e] + r * aH[e];           // = 2*log2e*y
            const float nn = 1.f - 2.f * __builtin_amdgcn_rcpf(1.f + __builtin_amdgcn_exp2f(y2));
            const float hv = nn + z * (h[e] - nn);
            h[e] = live ? hv : h[e];
            hp[e] = (_Float16)h[e];
        }
        *(uint2*)&A.c.hb[buf ^ 1][n][16 * wv + 4 * q] = *(uint2*)hp;
        __syncthreads();
    }

    const int prow = A.c.Psh[n];
    float4 o = make_float4(h[0], h[1], h[2], h[3]);
    *(float4*)&out[prow * HID + 16 * wv + 4 * q] = o;
}

extern "C" void kernel_launch(void* const* d_in, const int* in_sizes, int n_in,
                              void* d_out, int out_size, void* d_ws, size_t ws_size,
                              hipStream_t stream) {
    const int*   actor_ids  = (const int*)d_in[0];
    const int*   action_ids = (const int*)d_in[1];
    const int*   street_ids = (const int*)d_in[2];
    const float* bet        = (const float*)d_in[3];
    const int*   vmask      = (const int*)d_in[4];
    const float* E_actor    = (const float*)d_in[5];
    const float* E_action   = (const float*)d_in[6];
    const float* E_street   = (const float*)d_in[7];
    const float* W_proj     = (const float*)d_in[8];
    const float* b_proj     = (const float*)d_in[9];
    const float* W_ih       = (const float*)d_in[10];
    const float* W_hh       = (const float*)d_in[11];
    const float* b_ih       = (const float*)d_in[12];
    const float* b_hh       = (const float*)d_in[13];
    float*       out        = (float*)d_out;

    int* ws   = (int*)d_ws;
    int* lens = ws;
    int* perm = ws + NROWS;

    k_len<<<NROWS / 4, 256, 0, stream>>>(vmask, lens);
    k_sort<<<1, 1024, 0, stream>>>(lens, perm);

    gru_fused<<<NGRP, 256, 0, stream>>>(actor_ids, action_ids, street_ids, bet,
                                        E_actor, E_action, E_street,
                                        W_proj, b_proj, W_ih, b_ih, W_hh, b_hh,
                                        perm, lens, out);
}